// Round 2
// baseline (873.201 us; speedup 1.0000x reference)
//
#include <hip/hip_runtime.h>
#include <stdint.h>

constexpr int N_VOX = 1000000;
constexpr int NK = 27;
constexpr uint32_t PAIR_CAP = 4u * 1024u * 1024u;
constexpr int NBLK = (N_VOX + 255) / 256;

// ctrl layout (uint32): [0]=pairCursor, [32..63]=bucketCnt, [64..95]=bucketBase,
//                       [96..127]=bucketCursor, [128..159]=pairBase

__global__ __launch_bounds__(256) void init_ctrl(uint32_t* __restrict__ ctrl) {
  int t = blockIdx.x * 256 + threadIdx.x;
  if (t < 64) ctrl[t] = 0u;
}

// W0eff[k][c][co] = sum_j Wd0[k][c+8j][co]  (folds the channel-tile of x)
__global__ __launch_bounds__(256) void wreduce_k(const float* __restrict__ Wd0,
                                                 float* __restrict__ W0) {
  int i = blockIdx.x * 256 + threadIdx.x;
  if (i < NK * 8 * 32) {
    int k = i >> 8;          // / 256
    int r = i & 255;
    int c = r >> 5, co = r & 31;
    const float* b = Wd0 + k * 1024;
    W0[i] = b[c * 32 + co] + b[(c + 8) * 32 + co] + b[(c + 16) * 32 + co] +
            b[(c + 24) * 32 + co];
  }
}

__global__ __launch_bounds__(256) void build_csr(
    const uint8_t* __restrict__ msk, const int* __restrict__ nbr,
    uint32_t* __restrict__ offsets, uint32_t* __restrict__ counts,
    uint32_t* __restrict__ pairs, uint32_t* __restrict__ ctrl) {
  __shared__ uint32_t lhist[32];
  int n = blockIdx.x * 256 + threadIdx.x;
  if (threadIdx.x < 32) lhist[threadIdx.x] = 0u;
  __syncthreads();

  uint32_t mbits = 0u;
  uint32_t cnt = 0u;
  if (n < N_VOX) {
#pragma unroll
    for (int k = 0; k < NK; k++) {
      if (msk[(size_t)k * N_VOX + n]) { mbits |= (1u << k); cnt++; }
    }
  }

  // wave-64 inclusive scan of cnt
  unsigned lane = threadIdx.x & 63u;
  uint32_t pfx = cnt;
#pragma unroll
  for (int d = 1; d < 64; d <<= 1) {
    uint32_t v = __shfl_up(pfx, d);
    if (lane >= (unsigned)d) pfx += v;
  }
  uint32_t excl = pfx - cnt;
  uint32_t base = 0u;
  if (lane == 63u) base = atomicAdd(&ctrl[0], pfx);  // pfx on lane63 = wave total
  base = __shfl(base, 63);
  uint32_t off = base + excl;

  if (n < N_VOX) {
    offsets[n] = off;
    counts[n] = cnt;
    uint32_t w = off;
#pragma unroll
    for (int k = 0; k < NK; k++) {
      if (mbits & (1u << k)) {
        uint32_t src = (uint32_t)nbr[(size_t)k * N_VOX + n];
        if (w < PAIR_CAP) pairs[w] = ((uint32_t)k << 20) | src;
        w++;
      }
    }
    atomicAdd(&lhist[cnt], 1u);
  }
  __syncthreads();
  if (threadIdx.x < 32 && lhist[threadIdx.x])
    atomicAdd(&ctrl[32 + threadIdx.x], lhist[threadIdx.x]);
}

__global__ void scan_buckets(uint32_t* __restrict__ ctrl) {
  if (threadIdx.x == 0 && blockIdx.x == 0) {
    uint32_t* cnt = ctrl + 32;
    uint32_t* base = ctrl + 64;
    uint32_t* cur = ctrl + 96;
    uint32_t* pb = ctrl + 128;
    uint32_t vb = 0u, p = 0u;
    for (int c = 0; c < 32; c++) {
      base[c] = vb; cur[c] = vb; pb[c] = p;
      vb += cnt[c]; p += cnt[c] * (uint32_t)c;
    }
  }
}

__global__ __launch_bounds__(256) void build_perm(
    const uint32_t* __restrict__ counts, const uint32_t* __restrict__ offsets,
    const uint32_t* __restrict__ pairs, uint32_t* __restrict__ ctrl,
    uint64_t* __restrict__ perm, uint32_t* __restrict__ pairs2) {
  __shared__ uint32_t lhist[32];
  __shared__ uint32_t lbase[32];
  int n = blockIdx.x * 256 + threadIdx.x;
  if (threadIdx.x < 32) lhist[threadIdx.x] = 0u;
  __syncthreads();
  uint32_t c = 0u, lpos = 0u;
  if (n < N_VOX) {
    c = counts[n];
    lpos = atomicAdd(&lhist[c], 1u);
  }
  __syncthreads();
  if (threadIdx.x < 32)
    lbase[threadIdx.x] =
        lhist[threadIdx.x] ? atomicAdd(&ctrl[96 + threadIdx.x], lhist[threadIdx.x]) : 0u;
  __syncthreads();
  if (n < N_VOX) {
    uint32_t slot = lbase[c] + lpos;
    uint32_t rel = slot - ctrl[64 + c];          // - bucketBase[c]
    uint32_t poff = ctrl[128 + c] + rel * c;     // pairBase[c] + rel*c
    perm[slot] = (uint64_t)(uint32_t)n | ((uint64_t)c << 20) | ((uint64_t)poff << 25);
    uint32_t o = offsets[n];
    for (uint32_t j = 0; j < c; j++) {
      uint32_t d = poff + j, s = o + j;
      if (d < PAIR_CAP && s < PAIR_CAP) pairs2[d] = pairs[s];
    }
  }
}

enum { EPI_NONE = 0, EPI_RSUB = 1, EPI_ADDUP = 2 };

template <int CIN, int COUT, int EPI>
__global__ __launch_bounds__(256) void conv_k(
    const float* __restrict__ in, const float* __restrict__ Wg,
    const uint64_t* __restrict__ perm, const uint32_t* __restrict__ pairs2,
    const float* __restrict__ aux, float* __restrict__ out) {
  constexpr int WN = NK * CIN * COUT;
  constexpr bool BF16W = (WN * 4 > 61440);   // only the 32x32 conv
  constexpr int KSTR = CIN * COUT + 4;       // pad: keeps 16B align, spreads banks per k
  __shared__ float wf[BF16W ? 1 : NK * KSTR];
  __shared__ uint16_t wh[BF16W ? NK * KSTR : 1];

  for (int i = threadIdx.x; i < WN; i += 256) {
    int k = i / (CIN * COUT);
    int r = i - k * (CIN * COUT);
    float f = Wg[i];
    if constexpr (BF16W) {
      uint32_t u = __float_as_uint(f);
      wh[k * KSTR + r] = (uint16_t)((u + 0x7FFFu + ((u >> 16) & 1u)) >> 16);  // RNE
    } else {
      wf[k * KSTR + r] = f;
    }
  }
  __syncthreads();

  int i = blockIdx.x * 256 + threadIdx.x;
  if (i >= N_VOX) return;
  uint64_t e = perm[i];
  int dst = (int)(e & 0xFFFFFu);
  int cnt = (int)((e >> 20) & 31u);
  uint32_t poff = (uint32_t)(e >> 25);

  float acc[COUT];
#pragma unroll
  for (int co = 0; co < COUT; co++) acc[co] = 0.f;

  for (int j = 0; j < cnt; j++) {
    uint32_t pe = pairs2[poff + j];
    int k = (int)(pe >> 20);
    int src = (int)(pe & 0xFFFFFu);
    const float4* xr = (const float4*)(in + (size_t)src * CIN);
    float xv[CIN];
#pragma unroll
    for (int c4 = 0; c4 < CIN / 4; c4++) {
      float4 v = xr[c4];
      xv[c4 * 4 + 0] = v.x; xv[c4 * 4 + 1] = v.y;
      xv[c4 * 4 + 2] = v.z; xv[c4 * 4 + 3] = v.w;
    }
    if constexpr (!BF16W) {
      const float* wk = wf + k * KSTR;
#pragma unroll
      for (int ci = 0; ci < CIN; ci++) {
        float xc = xv[ci];
        const float* wr = wk + ci * COUT;
#pragma unroll
        for (int co = 0; co < COUT; co += 4) {
          float4 w = *(const float4*)(wr + co);
          acc[co + 0] += xc * w.x; acc[co + 1] += xc * w.y;
          acc[co + 2] += xc * w.z; acc[co + 3] += xc * w.w;
        }
      }
    } else {
      const uint16_t* wk = wh + k * KSTR;
#pragma unroll
      for (int ci = 0; ci < CIN; ci++) {
        float xc = xv[ci];
        const uint16_t* wr = wk + ci * COUT;
#pragma unroll
        for (int co = 0; co < COUT; co += 4) {
          uint2 u = *(const uint2*)(wr + co);
          acc[co + 0] += xc * __uint_as_float(u.x << 16);
          acc[co + 1] += xc * __uint_as_float(u.x & 0xFFFF0000u);
          acc[co + 2] += xc * __uint_as_float(u.y << 16);
          acc[co + 3] += xc * __uint_as_float(u.y & 0xFFFF0000u);
        }
      }
    }
  }

  float* op = out + (size_t)dst * COUT;
  if constexpr (EPI == EPI_NONE) {
#pragma unroll
    for (int co = 0; co < COUT; co += 4) {
      float4 v = {acc[co], acc[co + 1], acc[co + 2], acc[co + 3]};
      *(float4*)(op + co) = v;
    }
  } else if constexpr (EPI == EPI_RSUB) {  // out = aux - acc   (COUT==8)
    const float4* ar = (const float4*)(aux + (size_t)dst * 8);
    float4 a0 = ar[0], a1 = ar[1];
    float av[8] = {a0.x, a0.y, a0.z, a0.w, a1.x, a1.y, a1.z, a1.w};
#pragma unroll
    for (int co = 0; co < COUT; co += 4) {
      float4 v = {av[co] - acc[co], av[co + 1] - acc[co + 1],
                  av[co + 2] - acc[co + 2], av[co + 3] - acc[co + 3]};
      *(float4*)(op + co) = v;
    }
  } else {  // EPI_ADDUP: out = acc + tile(aux)   (COUT==32, aux row of 8)
    const float4* ar = (const float4*)(aux + (size_t)dst * 8);
    float4 a0 = ar[0], a1 = ar[1];
    float av[8] = {a0.x, a0.y, a0.z, a0.w, a1.x, a1.y, a1.z, a1.w};
#pragma unroll
    for (int co = 0; co < COUT; co += 4) {
      float4 v = {acc[co] + av[(co + 0) & 7], acc[co + 1] + av[(co + 1) & 7],
                  acc[co + 2] + av[(co + 2) & 7], acc[co + 3] + av[(co + 3) & 7]};
      *(float4*)(op + co) = v;
    }
  }
}

extern "C" void kernel_launch(void* const* d_in, const int* in_sizes, int n_in,
                              void* d_out, int out_size, void* d_ws, size_t ws_size,
                              hipStream_t stream) {
  const float* x = (const float*)d_in[0];
  const int* nbr = (const int*)d_in[1];
  const uint8_t* msk = (const uint8_t*)d_in[2];
  const float* Wd0 = (const float*)d_in[3];
  const float* Wd1 = (const float*)d_in[4];
  const float* Wd2 = (const float*)d_in[5];
  const float* Wu0 = (const float*)d_in[6];
  const float* Wu1 = (const float*)d_in[7];
  const float* Wu2 = (const float*)d_in[8];
  float* out = (float*)d_out;
  (void)in_sizes; (void)n_in; (void)out_size; (void)ws_size;

  char* ws = (char*)d_ws;
  size_t cur = 0;
  auto alloc = [&](size_t bytes) -> char* {
    char* p = ws + cur;
    cur = (cur + bytes + 255) & ~(size_t)255;
    return p;
  };
  uint32_t* pairs = (uint32_t*)alloc((size_t)PAIR_CAP * 4);
  uint32_t* pairs2 = (uint32_t*)alloc((size_t)PAIR_CAP * 4);
  uint32_t* offsets = (uint32_t*)alloc((size_t)N_VOX * 4);
  uint32_t* counts = (uint32_t*)alloc((size_t)N_VOX * 4);
  uint64_t* perm = (uint64_t*)alloc((size_t)N_VOX * 8);
  float* bufA = (float*)alloc((size_t)N_VOX * 32 * 4);
  float* bufB = (float*)alloc((size_t)N_VOX * 8 * 4);
  float* bufC = (float*)alloc((size_t)N_VOX * 8 * 4);
  float* W0eff = (float*)alloc((size_t)NK * 8 * 32 * 4);
  uint32_t* ctrl = (uint32_t*)alloc(1024);

  init_ctrl<<<1, 256, 0, stream>>>(ctrl);
  wreduce_k<<<27, 256, 0, stream>>>(Wd0, W0eff);
  build_csr<<<NBLK, 256, 0, stream>>>(msk, nbr, offsets, counts, pairs, ctrl);
  scan_buckets<<<1, 64, 0, stream>>>(ctrl);
  build_perm<<<NBLK, 256, 0, stream>>>(counts, offsets, pairs, ctrl, perm, pairs2);

  // d1 = conv(tile(x), Wd0) == conv(x, W0eff)        -> d_out (scratch use)
  conv_k<8, 32, EPI_NONE><<<NBLK, 256, 0, stream>>>(x, W0eff, perm, pairs2, nullptr, out);
  // d2 = conv(d1, Wd1)                               -> bufB
  conv_k<32, 8, EPI_NONE><<<NBLK, 256, 0, stream>>>(out, Wd1, perm, pairs2, nullptr, bufB);
  // r = x - conv(d2, Wd2)                            -> bufC
  conv_k<8, 8, EPI_RSUB><<<NBLK, 256, 0, stream>>>(bufB, Wd2, perm, pairs2, x, bufC);
  // r1 = conv(r, Wu0)                                -> bufB
  conv_k<8, 8, EPI_NONE><<<NBLK, 256, 0, stream>>>(bufC, Wu0, perm, pairs2, nullptr, bufB);
  // r2 = conv(r1, Wu1)                               -> bufA
  conv_k<8, 32, EPI_NONE><<<NBLK, 256, 0, stream>>>(bufB, Wu1, perm, pairs2, nullptr, bufA);
  // out = tile(x) + conv(r2, Wu2)                    -> d_out
  conv_k<32, 32, EPI_ADDUP><<<NBLK, 256, 0, stream>>>(bufA, Wu2, perm, pairs2, x, out);
}

// Round 3
// 695.485 us; speedup vs baseline: 1.2555x; 1.2555x over previous
//
#include <hip/hip_runtime.h>
#include <stdint.h>

constexpr int N_VOX = 1000000;
constexpr int NK = 27;
constexpr uint32_t PAIR_CAP = 4u * 1024u * 1024u;
constexpr int VPB = 1024;                        // voxels per build block (4/thread)
constexpr int NB = (N_VOX + VPB - 1) / VPB;      // 977
constexpr int NBLK = (N_VOX + 255) / 256;        // conv grid

// ---------------- build pipeline (deterministic, no global atomics) -------

// Pass 1: mbits + per-block bucket histogram (bucket = popcount = pair count)
__global__ __launch_bounds__(256) void count_mbits(
    const uint8_t* __restrict__ msk, uint32_t* __restrict__ mbits,
    uint32_t* __restrict__ blockHist) {
  __shared__ uint32_t lhist[32];
  if (threadIdx.x < 32) lhist[threadIdx.x] = 0u;
  __syncthreads();
  int n0 = blockIdx.x * VPB + threadIdx.x * 4;
  uint32_t m[4] = {0u, 0u, 0u, 0u};
  if (n0 + 3 < N_VOX) {
#pragma unroll
    for (int k = 0; k < NK; k++) {
      uint32_t u = *(const uint32_t*)(msk + (size_t)k * N_VOX + n0);
      m[0] |= (u & 1u) << k;
      m[1] |= ((u >> 8) & 1u) << k;
      m[2] |= ((u >> 16) & 1u) << k;
      m[3] |= ((u >> 24) & 1u) << k;
    }
    atomicAdd(&lhist[__popc(m[0])], 1u);
    atomicAdd(&lhist[__popc(m[1])], 1u);
    atomicAdd(&lhist[__popc(m[2])], 1u);
    atomicAdd(&lhist[__popc(m[3])], 1u);
  } else {
#pragma unroll 1
    for (int i = 0; i < 4; i++) {
      int n = n0 + i;
      if (n < N_VOX) {
        uint32_t mm = 0u;
        for (int k = 0; k < NK; k++)
          mm |= (uint32_t)(msk[(size_t)k * N_VOX + n] != 0) << k;
        m[i] = mm;
        atomicAdd(&lhist[__popc(mm)], 1u);
      }
    }
  }
  *(uint4*)(mbits + n0) = make_uint4(m[0], m[1], m[2], m[3]);  // padded alloc
  __syncthreads();
  if (threadIdx.x < 32) blockHist[blockIdx.x * 32 + threadIdx.x] = lhist[threadIdx.x];
}

// Pass 2: column scans (per bucket over blocks) + bucket bases. One block.
// ctrl: [0..31] bucketSlotBase, [32..63] bucketPairBase
__global__ __launch_bounds__(1024) void scan_blocks(
    const uint32_t* __restrict__ blockHist, uint32_t* __restrict__ relBase,
    uint32_t* __restrict__ ctrl) {
  __shared__ uint32_t totals[32];
  __shared__ uint32_t sBase[32], sPair[32];
  int wave = threadIdx.x >> 6;
  int lane = threadIdx.x & 63;
  for (int c = wave; c < 32; c += 16) {
    uint32_t carry = 0u;
#pragma unroll 1
    for (int chunk = 0; chunk < (NB + 63) / 64; chunk++) {
      int b = chunk * 64 + lane;
      uint32_t v = (b < NB) ? blockHist[b * 32 + c] : 0u;
      uint32_t s = v;
#pragma unroll
      for (int d = 1; d < 64; d <<= 1) {
        uint32_t t = __shfl_up(s, d);
        if (lane >= d) s += t;
      }
      if (b < NB) relBase[b * 32 + c] = carry + s - v;  // exclusive within bucket
      carry += __shfl(s, 63);
    }
    if (lane == 0) totals[c] = carry;
  }
  __syncthreads();
  if (threadIdx.x == 0) {
    uint32_t vb = 0u, pb = 0u;
    for (int c = 0; c < 32; c++) {
      sBase[c] = vb; sPair[c] = pb;
      vb += totals[c]; pb += totals[c] * (uint32_t)c;
    }
  }
  __syncthreads();
  if (threadIdx.x < 32) {
    ctrl[threadIdx.x] = sBase[threadIdx.x];
    ctrl[32 + threadIdx.x] = sPair[threadIdx.x];
  }
}

// Pass 3: assign slots (LDS-local ranking only) and write perm + final pairs
__global__ __launch_bounds__(256) void fill_pairs(
    const uint32_t* __restrict__ mbits, const int* __restrict__ nbr,
    const uint32_t* __restrict__ relBase, const uint32_t* __restrict__ ctrl,
    uint64_t* __restrict__ perm, uint32_t* __restrict__ pairs2) {
  __shared__ uint32_t lhist[32];
  __shared__ uint32_t bb[32], pb[32], rb[32];
  if (threadIdx.x < 32) {
    lhist[threadIdx.x] = 0u;
    bb[threadIdx.x] = ctrl[threadIdx.x];
    pb[threadIdx.x] = ctrl[32 + threadIdx.x];
    rb[threadIdx.x] = relBase[blockIdx.x * 32 + threadIdx.x];
  }
  __syncthreads();
  int n0 = blockIdx.x * VPB + threadIdx.x * 4;
  uint4 mv = *(const uint4*)(mbits + n0);  // padded alloc
  uint32_t m[4] = {mv.x, mv.y, mv.z, mv.w};
  uint32_t cn[4], lp[4];
#pragma unroll
  for (int i = 0; i < 4; i++) {
    int n = n0 + i;
    cn[i] = (uint32_t)__popc(m[i]);
    lp[i] = 0u;
    if (n < N_VOX) lp[i] = atomicAdd(&lhist[cn[i]], 1u);
  }
#pragma unroll
  for (int i = 0; i < 4; i++) {
    int n = n0 + i;
    if (n >= N_VOX) continue;
    uint32_t c = cn[i];
    uint32_t rel = rb[c] + lp[i];
    uint32_t slot = bb[c] + rel;
    uint32_t poff = pb[c] + rel * c;
    perm[slot] = (uint64_t)(uint32_t)n | ((uint64_t)c << 20) | ((uint64_t)poff << 25);
    uint32_t mm = m[i];
    uint32_t w = poff;
    while (mm) {
      int k = __ffs(mm) - 1;
      mm &= mm - 1u;
      uint32_t src = (uint32_t)nbr[(size_t)k * N_VOX + n];
      if (w < PAIR_CAP) pairs2[w] = ((uint32_t)k << 20) | src;
      w++;
    }
  }
}

// ---------------- weight prep --------------------------------------------

// W0eff[k][c][co] = sum_j Wd0[k][c+8j][co]  (folds the channel-tile of x)
__global__ __launch_bounds__(256) void wreduce_k(const float* __restrict__ Wd0,
                                                 float* __restrict__ W0) {
  int i = blockIdx.x * 256 + threadIdx.x;
  if (i < NK * 8 * 32) {
    int k = i >> 8;
    int r = i & 255;
    int c = r >> 5, co = r & 31;
    const float* b = Wd0 + k * 1024;
    W0[i] = b[c * 32 + co] + b[(c + 8) * 32 + co] + b[(c + 16) * 32 + co] +
            b[(c + 24) * 32 + co];
  }
}

// ---------------- convs ---------------------------------------------------

enum { EPI_NONE = 0, EPI_RSUB = 1, EPI_ADDUP = 2 };

template <int CIN, int COUT, int EPI>
__global__ __launch_bounds__(256) void conv_k(
    const float* __restrict__ in, const float* __restrict__ Wg,
    const uint64_t* __restrict__ perm, const uint32_t* __restrict__ pairs2,
    const float* __restrict__ aux, float* __restrict__ out) {
  constexpr int WN = NK * CIN * COUT;
  constexpr bool BF16W = (WN * 4 > 61440);   // only the 32x32 conv
  constexpr int KSTR = CIN * COUT + 4;       // 16B-align + odd-16B-slot k rotation
  __shared__ float wf[BF16W ? 1 : NK * KSTR];
  __shared__ uint16_t wh[BF16W ? NK * KSTR : 1];

  for (int i = threadIdx.x; i < WN; i += 256) {
    int k = i / (CIN * COUT);
    int r = i - k * (CIN * COUT);
    float f = Wg[i];
    if constexpr (BF16W) {
      uint32_t u = __float_as_uint(f);
      wh[k * KSTR + r] = (uint16_t)((u + 0x7FFFu + ((u >> 16) & 1u)) >> 16);  // RNE
    } else {
      wf[k * KSTR + r] = f;
    }
  }
  __syncthreads();

  int i = blockIdx.x * 256 + threadIdx.x;
  if (i >= N_VOX) return;
  uint64_t e = perm[i];
  int dst = (int)(e & 0xFFFFFu);
  int cnt = (int)((e >> 20) & 31u);
  uint32_t poff = (uint32_t)(e >> 25);

  float acc[COUT];
#pragma unroll
  for (int co = 0; co < COUT; co++) acc[co] = 0.f;

  for (int j = 0; j < cnt; j++) {
    uint32_t pe = pairs2[poff + j];
    int k = (int)(pe >> 20);
    int src = (int)(pe & 0xFFFFFu);
    const float4* xr = (const float4*)(in + (size_t)src * CIN);
    float xv[CIN];
#pragma unroll
    for (int c4 = 0; c4 < CIN / 4; c4++) {
      float4 v = xr[c4];
      xv[c4 * 4 + 0] = v.x; xv[c4 * 4 + 1] = v.y;
      xv[c4 * 4 + 2] = v.z; xv[c4 * 4 + 3] = v.w;
    }
    if constexpr (!BF16W) {
      const float* wk = wf + k * KSTR;
#pragma unroll
      for (int ci = 0; ci < CIN; ci++) {
        float xc = xv[ci];
        const float* wr = wk + ci * COUT;
#pragma unroll
        for (int co = 0; co < COUT; co += 4) {
          float4 w = *(const float4*)(wr + co);
          acc[co + 0] += xc * w.x; acc[co + 1] += xc * w.y;
          acc[co + 2] += xc * w.z; acc[co + 3] += xc * w.w;
        }
      }
    } else {
      const uint16_t* wk = wh + k * KSTR;
#pragma unroll
      for (int ci = 0; ci < CIN; ci++) {
        float xc = xv[ci];
        const uint16_t* wr = wk + ci * COUT;
#pragma unroll
        for (int co = 0; co < COUT; co += 4) {
          uint2 u = *(const uint2*)(wr + co);
          acc[co + 0] += xc * __uint_as_float(u.x << 16);
          acc[co + 1] += xc * __uint_as_float(u.x & 0xFFFF0000u);
          acc[co + 2] += xc * __uint_as_float(u.y << 16);
          acc[co + 3] += xc * __uint_as_float(u.y & 0xFFFF0000u);
        }
      }
    }
  }

  float* op = out + (size_t)dst * COUT;
  if constexpr (EPI == EPI_NONE) {
#pragma unroll
    for (int co = 0; co < COUT; co += 4) {
      float4 v = {acc[co], acc[co + 1], acc[co + 2], acc[co + 3]};
      *(float4*)(op + co) = v;
    }
  } else if constexpr (EPI == EPI_RSUB) {  // out = aux - acc   (COUT==8)
    const float4* ar = (const float4*)(aux + (size_t)dst * 8);
    float4 a0 = ar[0], a1 = ar[1];
    float av[8] = {a0.x, a0.y, a0.z, a0.w, a1.x, a1.y, a1.z, a1.w};
#pragma unroll
    for (int co = 0; co < COUT; co += 4) {
      float4 v = {av[co] - acc[co], av[co + 1] - acc[co + 1],
                  av[co + 2] - acc[co + 2], av[co + 3] - acc[co + 3]};
      *(float4*)(op + co) = v;
    }
  } else {  // EPI_ADDUP: out = acc + tile(aux)   (COUT==32, aux row of 8)
    const float4* ar = (const float4*)(aux + (size_t)dst * 8);
    float4 a0 = ar[0], a1 = ar[1];
    float av[8] = {a0.x, a0.y, a0.z, a0.w, a1.x, a1.y, a1.z, a1.w};
#pragma unroll
    for (int co = 0; co < COUT; co += 4) {
      float4 v = {acc[co] + av[(co + 0) & 7], acc[co + 1] + av[(co + 1) & 7],
                  acc[co + 2] + av[(co + 2) & 7], acc[co + 3] + av[(co + 3) & 7]};
      *(float4*)(op + co) = v;
    }
  }
}

// ---------------- launcher ------------------------------------------------

extern "C" void kernel_launch(void* const* d_in, const int* in_sizes, int n_in,
                              void* d_out, int out_size, void* d_ws, size_t ws_size,
                              hipStream_t stream) {
  const float* x = (const float*)d_in[0];
  const int* nbr = (const int*)d_in[1];
  const uint8_t* msk = (const uint8_t*)d_in[2];
  const float* Wd0 = (const float*)d_in[3];
  const float* Wd1 = (const float*)d_in[4];
  const float* Wd2 = (const float*)d_in[5];
  const float* Wu0 = (const float*)d_in[6];
  const float* Wu1 = (const float*)d_in[7];
  const float* Wu2 = (const float*)d_in[8];
  float* out = (float*)d_out;
  (void)in_sizes; (void)n_in; (void)out_size; (void)ws_size;

  char* ws = (char*)d_ws;
  size_t cur = 0;
  auto alloc = [&](size_t bytes) -> char* {
    char* p = ws + cur;
    cur = (cur + bytes + 255) & ~(size_t)255;
    return p;
  };
  uint32_t* pairs2 = (uint32_t*)alloc((size_t)PAIR_CAP * 4);
  uint32_t* mbits = (uint32_t*)alloc((size_t)NB * VPB * 4);
  uint32_t* blockHist = (uint32_t*)alloc((size_t)NB * 32 * 4);
  uint32_t* relBase = (uint32_t*)alloc((size_t)NB * 32 * 4);
  uint64_t* perm = (uint64_t*)alloc((size_t)N_VOX * 8);
  float* bufA = (float*)alloc((size_t)N_VOX * 32 * 4);
  float* bufB = (float*)alloc((size_t)N_VOX * 8 * 4);
  float* bufC = (float*)alloc((size_t)N_VOX * 8 * 4);
  float* W0eff = (float*)alloc((size_t)NK * 8 * 32 * 4);
  uint32_t* ctrl = (uint32_t*)alloc(1024);

  wreduce_k<<<27, 256, 0, stream>>>(Wd0, W0eff);
  count_mbits<<<NB, 256, 0, stream>>>(msk, mbits, blockHist);
  scan_blocks<<<1, 1024, 0, stream>>>(blockHist, relBase, ctrl);
  fill_pairs<<<NB, 256, 0, stream>>>(mbits, nbr, relBase, ctrl, perm, pairs2);

  // d1 = conv(tile(x), Wd0) == conv(x, W0eff)        -> d_out (scratch use)
  conv_k<8, 32, EPI_NONE><<<NBLK, 256, 0, stream>>>(x, W0eff, perm, pairs2, nullptr, out);
  // d2 = conv(d1, Wd1)                               -> bufB
  conv_k<32, 8, EPI_NONE><<<NBLK, 256, 0, stream>>>(out, Wd1, perm, pairs2, nullptr, bufB);
  // r = x - conv(d2, Wd2)                            -> bufC
  conv_k<8, 8, EPI_RSUB><<<NBLK, 256, 0, stream>>>(bufB, Wd2, perm, pairs2, x, bufC);
  // r1 = conv(r, Wu0)                                -> bufB
  conv_k<8, 8, EPI_NONE><<<NBLK, 256, 0, stream>>>(bufC, Wu0, perm, pairs2, nullptr, bufB);
  // r2 = conv(r1, Wu1)                               -> bufA
  conv_k<8, 32, EPI_NONE><<<NBLK, 256, 0, stream>>>(bufB, Wu1, perm, pairs2, nullptr, bufA);
  // out = tile(x) + conv(r2, Wu2)                    -> d_out
  conv_k<32, 32, EPI_ADDUP><<<NBLK, 256, 0, stream>>>(bufA, Wu2, perm, pairs2, x, out);
}